// Round 1
// baseline (583.026 us; speedup 1.0000x reference)
//
#include <hip/hip_runtime.h>
#include <hip/hip_bf16.h>

#define BT_ 8192   // B*T
#define D_  512
#define V_  8192

// d_out float offsets (outputs concatenated in return order)
#define OFF_Q      0
#define OFF_TOK    4194304
#define OFF_LOSS   4202496
#define OFF_SOFT   4202497
#define OFF_LOGITS 71311361
// bf16 staging scratch inside soft region, 16B-aligned float offset
#define STAGE_F    4202500

#define TAU  0.02f
#define MAXC 128

typedef __attribute__((ext_vector_type(8))) short bf16x8;
typedef __attribute__((ext_vector_type(4))) float f32x4;
typedef __attribute__((ext_vector_type(4))) unsigned short u16x4;

__device__ __forceinline__ unsigned short bf16rne(float f) {
  unsigned int u = __float_as_uint(f);
  return (unsigned short)((u + 0x7fffu + ((u >> 16) & 1u)) >> 16);
}

// ---------------- pass 0: fp32 -> bf16 for X and W ----------------
__global__ __launch_bounds__(256) void to_bf16_k(const float4* __restrict__ x,
                                                 const float4* __restrict__ w,
                                                 u16x4* __restrict__ xa,
                                                 u16x4* __restrict__ wb) {
  const int n4 = (BT_ * D_) / 4;  // 1048576 float4 per tensor
  for (int i = blockIdx.x * 256 + threadIdx.x; i < 2 * n4; i += gridDim.x * 256) {
    const int isw = i >= n4;
    const int j = isw ? i - n4 : i;
    const float4 v = isw ? w[j] : x[j];
    u16x4 o;
    o[0] = bf16rne(v.x); o[1] = bf16rne(v.y);
    o[2] = bf16rne(v.z); o[3] = bf16rne(v.w);
    (isw ? wb : xa)[j] = o;
  }
}

// ---------------- pass 1: bf16 MFMA GEMM, logits = X*W^T + b ----------------
__device__ __forceinline__ void gload_lds16(const void* g, void* l) {
  __builtin_amdgcn_global_load_lds((const __attribute__((address_space(1))) void*)g,
                                   (__attribute__((address_space(3))) void*)l,
                                   16, 0, 0);
}

__global__ __launch_bounds__(256) void gemm_logits(const unsigned short* __restrict__ A,
                                                   const unsigned short* __restrict__ B,
                                                   const float* __restrict__ bias,
                                                   float* __restrict__ C) {
  __shared__ unsigned short sA[128 * 64];  // 16 KB
  __shared__ unsigned short sB[128 * 64];  // 16 KB
  const int tid  = threadIdx.x;
  const int lane = tid & 63;
  const int wv   = tid >> 6;          // 4 waves
  const int row0 = blockIdx.y * 128;
  const int col0 = blockIdx.x * 128;
  const int wr = wv >> 1, wc = wv & 1;  // 2x2 wave grid, 64x64 per wave

  f32x4 acc[4][4] = {};

  const char* Abase = (const char*)A + (size_t)row0 * (D_ * 2);
  const char* Bbase = (const char*)B + (size_t)col0 * (D_ * 2);

  for (int k0 = 0; k0 < D_; k0 += 64) {
    // stage 128x64 bf16 tiles of A and B: 4 issues x 4 waves x 1KB each
#pragma unroll
    for (int j = 0; j < 4; ++j) {
      const int lbase = j * 4096 + wv * 1024;       // wave-uniform LDS byte base
      const int ff = lbase + lane * 16;             // this lane's tile byte
      const int r  = ff >> 7;                       // tile row (128B per row)
      const int cb = ff & 127;                      // byte within row
      const size_t goff = (size_t)r * (D_ * 2) + (size_t)(k0 * 2) + cb;
      gload_lds16(Abase + goff, (char*)sA + lbase);
      gload_lds16(Bbase + goff, (char*)sB + lbase);
    }
    __syncthreads();
#pragma unroll
    for (int kk = 0; kk < 64; kk += 32) {
      const int koff = kk + 8 * (lane >> 4);
      bf16x8 af[4], bfr[4];
#pragma unroll
      for (int m = 0; m < 4; ++m)
        af[m] = *(const bf16x8*)(sA + (wr * 64 + m * 16 + (lane & 15)) * 64 + koff);
#pragma unroll
      for (int n = 0; n < 4; ++n)
        bfr[n] = *(const bf16x8*)(sB + (wc * 64 + n * 16 + (lane & 15)) * 64 + koff);
#pragma unroll
      for (int m = 0; m < 4; ++m)
#pragma unroll
        for (int n = 0; n < 4; ++n)
          acc[m][n] = __builtin_amdgcn_mfma_f32_16x16x32_bf16(af[m], bfr[n], acc[m][n], 0, 0, 0);
    }
    __syncthreads();
  }

  // epilogue: C[row][col] = acc + bias ; C/D layout: col=lane&15, row=4*(lane>>4)+reg
#pragma unroll
  for (int n = 0; n < 4; ++n) {
    const int col = col0 + wc * 64 + n * 16 + (lane & 15);
    const float bv = bias[col];
#pragma unroll
    for (int m = 0; m < 4; ++m) {
      const int rbase = row0 + wr * 64 + m * 16 + 4 * (lane >> 4);
#pragma unroll
      for (int r = 0; r < 4; ++r)
        C[(size_t)(rbase + r) * V_ + col] = acc[m][n][r] + bv;
    }
  }
}

// ---------------- pass 2: per-row sum(exp), argmax with exact-fp32 rescue ----------------
__global__ __launch_bounds__(256) void row_stats(const float* __restrict__ logits,
                                                 const float* __restrict__ xf,
                                                 const float* __restrict__ wf,
                                                 const float* __restrict__ bias,
                                                 float* __restrict__ tokf,
                                                 float* __restrict__ sinv) {
  __shared__ float Ls[V_];  // 32 KB row stage
  __shared__ float redm[4], reds[4], dred[4];
  __shared__ int cnum;
  __shared__ int cidx[MAXC];
  const int tid  = threadIdx.x;
  const int lane = tid & 63;
  const int wv   = tid >> 6;
  const int row  = blockIdx.x;
  const float* L = logits + (size_t)row * V_;

  float m = -1e30f, s = 0.f;
  for (int i = tid; i < V_; i += 256) {
    const float v = L[i];
    Ls[i] = v;
    m = fmaxf(m, v);
    s += __expf(v);   // |logit| < ~3 -> no shift needed, fp32 safe
  }
#pragma unroll
  for (int o = 32; o; o >>= 1) {
    m = fmaxf(m, __shfl_xor(m, o));
    s += __shfl_xor(s, o);
  }
  if (lane == 0) { redm[wv] = m; reds[wv] = s; }
  if (tid == 0) cnum = 0;
  __syncthreads();
  m = fmaxf(fmaxf(redm[0], redm[1]), fmaxf(redm[2], redm[3]));
  s = reds[0] + reds[1] + reds[2] + reds[3];

  // candidates within TAU of approx max (bf16 error << TAU)
  const float thr = m - TAU;
  for (int i = tid; i < V_; i += 256) {
    if (Ls[i] >= thr) {
      const int p = atomicAdd(&cnum, 1);
      if (p < MAXC) cidx[p] = i;
    }
  }
  __syncthreads();
  const int cnt = min(cnum, MAXC);
  float bestv = -1e30f;
  int besti = 0x7fffffff;
  const float* xr = xf + (size_t)row * D_;
  for (int c = 0; c < cnt; ++c) {
    const int col = cidx[c];
    const float* wr = wf + (size_t)col * D_;
    float p = 0.f;
    for (int k = tid; k < D_; k += 256) p += xr[k] * wr[k];
#pragma unroll
    for (int o = 32; o; o >>= 1) p += __shfl_xor(p, o);
    if (lane == 0) dred[wv] = p;
    __syncthreads();
    const float tot = dred[0] + dred[1] + dred[2] + dred[3] + bias[col];
    if (tot > bestv || (tot == bestv && col < besti)) { bestv = tot; besti = col; }
    __syncthreads();
  }
  if (tid == 0) {
    tokf[row] = (float)besti;   // token_indices output (as float)
    sinv[row] = 1.0f / s;
  }
}

// ---------------- pass 3: soft = exp(logit) * sinv[row] ----------------
__global__ __launch_bounds__(256) void softmax_apply(const float* __restrict__ logits,
                                                     const float* __restrict__ sinv,
                                                     float* __restrict__ soft) {
  const size_t total = (size_t)BT_ * V_;
  for (size_t i = (size_t)blockIdx.x * 256 + threadIdx.x; i < total;
       i += (size_t)gridDim.x * 256) {
    const int row = (int)(i >> 13);
    soft[i] = __expf(logits[i]) * sinv[row];
  }
}

// ---------------- pass 4: quantized gather + commitment loss ----------------
__global__ __launch_bounds__(256) void finalize_k(const float* __restrict__ tokf,
                                                  const float* __restrict__ cb,
                                                  const float* __restrict__ xf,
                                                  float* __restrict__ q,
                                                  float* __restrict__ loss) {
  const int row  = blockIdx.x * 4 + (threadIdx.x >> 6);  // one wave per row
  const int lane = threadIdx.x & 63;
  const int idx  = (int)tokf[row];
  const float4* cr = (const float4*)(cb + (size_t)idx * D_);
  const float4* xr = (const float4*)(xf + (size_t)row * D_);
  float4* qr = (float4*)(q + (size_t)row * D_);
  float ls = 0.f;
#pragma unroll
  for (int j = 0; j < 2; ++j) {
    const int c = lane + j * 64;  // 128 float4 per row
    const float4 cv = cr[c];
    const float4 xv = xr[c];
    qr[c] = cv;
    const float dx = cv.x - xv.x, dy = cv.y - xv.y, dz = cv.z - xv.z, dw = cv.w - xv.w;
    ls += dx * dx + dy * dy + dz * dz + dw * dw;
  }
#pragma unroll
  for (int o = 32; o; o >>= 1) ls += __shfl_xor(ls, o);
  if (lane == 0) atomicAdd(loss, ls * (1.0f / 4194304.0f));
}

extern "C" void kernel_launch(void* const* d_in, const int* in_sizes, int n_in,
                              void* d_out, int out_size, void* d_ws, size_t ws_size,
                              hipStream_t stream) {
  const float* x  = (const float*)d_in[0];  // inputs   [8192][512]
  const float* cb = (const float*)d_in[1];  // codebook [8192][512]
  const float* wl = (const float*)d_in[2];  // W_logits [8192][512]
  const float* bl = (const float*)d_in[3];  // b_logits [8192]
  float* out = (float*)d_out;

  float* qout   = out + OFF_Q;
  float* tokf   = out + OFF_TOK;
  float* loss   = out + OFF_LOSS;
  float* soft   = out + OFF_SOFT;
  float* logits = out + OFF_LOGITS;

  // scratch: bf16 staging in soft region (overwritten by pass 3),
  //          sinv in quantized region (overwritten by pass 4)
  unsigned short* Abf = (unsigned short*)(out + STAGE_F);
  unsigned short* Wbf = Abf + (size_t)BT_ * D_;
  float* sinv = qout;

  hipMemsetAsync(loss, 0, 4, stream);  // loss accumulator = 0 each call

  to_bf16_k<<<2048, 256, 0, stream>>>((const float4*)x, (const float4*)wl,
                                      (u16x4*)Abf, (u16x4*)Wbf);
  gemm_logits<<<dim3(64, 64), 256, 0, stream>>>(Abf, Wbf, bl, logits);
  row_stats<<<8192, 256, 0, stream>>>(logits, x, wl, bl, tokf, sinv);
  softmax_apply<<<2048, 256, 0, stream>>>(logits, sinv, soft);
  finalize_k<<<2048, 256, 0, stream>>>(tokf, cb, x, qout, loss);
}

// Round 2
// 433.599 us; speedup vs baseline: 1.3446x; 1.3446x over previous
//
#include <hip/hip_runtime.h>
#include <hip/hip_bf16.h>

#define BT_ 8192   // B*T
#define D_  512
#define V_  8192
#define NTILE 64   // V / 128 col-tiles

// d_out float offsets (outputs concatenated in return order)
#define OFF_Q      0
#define OFF_TOK    4194304
#define OFF_LOSS   4202496
#define OFF_SOFT   4202497
#define OFF_LOGITS 71311361
// bf16 staging scratch inside soft region, 16B-aligned float offset
#define STAGE_F    4202500

#define TAU  0.02f

typedef __attribute__((ext_vector_type(8))) short bf16x8;
typedef __attribute__((ext_vector_type(4))) float f32x4;
typedef __attribute__((ext_vector_type(4))) unsigned short u16x4;

__device__ __forceinline__ unsigned short bf16rne(float f) {
  unsigned int u = __float_as_uint(f);
  return (unsigned short)((u + 0x7fffu + ((u >> 16) & 1u)) >> 16);
}

// ---------------- pass 0: fp32 -> bf16 for X and W ----------------
__global__ __launch_bounds__(256) void to_bf16_k(const float4* __restrict__ x,
                                                 const float4* __restrict__ w,
                                                 u16x4* __restrict__ xa,
                                                 u16x4* __restrict__ wb) {
  const int n4 = (BT_ * D_) / 4;
  for (int i = blockIdx.x * 256 + threadIdx.x; i < 2 * n4; i += gridDim.x * 256) {
    const int isw = i >= n4;
    const int j = isw ? i - n4 : i;
    const float4 v = isw ? w[j] : x[j];
    u16x4 o;
    o[0] = bf16rne(v.x); o[1] = bf16rne(v.y);
    o[2] = bf16rne(v.z); o[3] = bf16rne(v.w);
    (isw ? wb : xa)[j] = o;
  }
}

// ---------------- pass 1: bf16 MFMA GEMM + per-tile row stats ----------------
__device__ __forceinline__ void gload_lds16(const void* g, void* l) {
  __builtin_amdgcn_global_load_lds((const __attribute__((address_space(1))) void*)g,
                                   (__attribute__((address_space(3))) void*)l,
                                   16, 0, 0);
}

__global__ __launch_bounds__(256) void gemm_logits(const unsigned short* __restrict__ A,
                                                   const unsigned short* __restrict__ B,
                                                   const float* __restrict__ bias,
                                                   float* __restrict__ C,
                                                   float* __restrict__ pmaxG,
                                                   float* __restrict__ psumG) {
  __shared__ unsigned short sA[128 * 64];  // 16 KB
  __shared__ unsigned short sB[128 * 64];  // 16 KB
  const int tid  = threadIdx.x;
  const int lane = tid & 63;
  const int wv   = tid >> 6;
  const int row0 = blockIdx.y * 128;
  const int col0 = blockIdx.x * 128;
  const int wr = wv >> 1, wc = wv & 1;  // 2x2 wave grid, 64x64 per wave

  f32x4 acc[4][4] = {};

  const char* Abase = (const char*)A + (size_t)row0 * (D_ * 2);
  const char* Bbase = (const char*)B + (size_t)col0 * (D_ * 2);

  for (int k0 = 0; k0 < D_; k0 += 64) {
#pragma unroll
    for (int j = 0; j < 4; ++j) {
      const int lbase = j * 4096 + wv * 1024;       // wave-uniform LDS byte base
      const int ff = lbase + lane * 16;
      const int r  = ff >> 7;
      const int cb = ff & 127;
      const size_t goff = (size_t)r * (D_ * 2) + (size_t)(k0 * 2) + cb;
      gload_lds16(Abase + goff, (char*)sA + lbase);
      gload_lds16(Bbase + goff, (char*)sB + lbase);
    }
    __syncthreads();
#pragma unroll
    for (int kk = 0; kk < 64; kk += 32) {
      const int koff = kk + 8 * (lane >> 4);
      bf16x8 af[4], bfr[4];
#pragma unroll
      for (int m = 0; m < 4; ++m)
        af[m] = *(const bf16x8*)(sA + (wr * 64 + m * 16 + (lane & 15)) * 64 + koff);
#pragma unroll
      for (int n = 0; n < 4; ++n)
        bfr[n] = *(const bf16x8*)(sB + (wc * 64 + n * 16 + (lane & 15)) * 64 + koff);
#pragma unroll
      for (int m = 0; m < 4; ++m)
#pragma unroll
        for (int n = 0; n < 4; ++n)
          acc[m][n] = __builtin_amdgcn_mfma_f32_16x16x32_bf16(af[m], bfr[n], acc[m][n], 0, 0, 0);
    }
    __syncthreads();   // also guards sA reuse as stats scratch below
  }

  // epilogue: write C, accumulate per-row {max, sum(exp)} over this block's 128 cols
  float* pmS = (float*)sA;        // [2][128] max   (sA free after last barrier)
  float* psS = pmS + 256;         // [2][128] sumexp

  const int gcol = col0 + wc * 64 + (lane & 15);
  float bv[4];
#pragma unroll
  for (int n = 0; n < 4; ++n) bv[n] = bias[gcol + n * 16];

#pragma unroll
  for (int m = 0; m < 4; ++m) {
    const int rib0 = wr * 64 + m * 16 + 4 * (lane >> 4);
#pragma unroll
    for (int r = 0; r < 4; ++r) {
      const size_t rowg = row0 + rib0 + r;
      float vmx = -1e30f, vsm = 0.f;
#pragma unroll
      for (int n = 0; n < 4; ++n) {
        const float v = acc[m][n][r] + bv[n];
        C[rowg * V_ + gcol + n * 16] = v;
        vmx = fmaxf(vmx, v);
        vsm += __expf(v);
      }
#pragma unroll
      for (int o = 1; o < 16; o <<= 1) {   // reduce across the 16-lane col group
        vmx = fmaxf(vmx, __shfl_xor(vmx, o));
        vsm += __shfl_xor(vsm, o);
      }
      if ((lane & 15) == 0) {
        pmS[wc * 128 + rib0 + r] = vmx;
        psS[wc * 128 + rib0 + r] = vsm;
      }
    }
  }
  __syncthreads();
  if (tid < 128) {
    const float mx = fmaxf(pmS[tid], pmS[128 + tid]);
    const float sm = psS[tid] + psS[128 + tid];
    pmaxG[(size_t)(row0 + tid) * NTILE + blockIdx.x] = mx;
    psumG[(size_t)(row0 + tid) * NTILE + blockIdx.x] = sm;
  }
}

// ---- pass 2: per-row reduce partials, exact-fp32 argmax rescue, softmax sweep ----
__global__ __launch_bounds__(256) void row_finish(const float* __restrict__ logits,
                                                  const float* __restrict__ pmaxG,
                                                  const float* __restrict__ psumG,
                                                  const float* __restrict__ xf,
                                                  const float* __restrict__ wf,
                                                  const float* __restrict__ bias,
                                                  float* __restrict__ tokf,
                                                  float* __restrict__ soft) {
  const int row  = blockIdx.x;
  const int tid  = threadIdx.x;
  const int lane = tid & 63;
  __shared__ float sinv_s;

  if (tid < 64) {  // wave 0: stats + argmax rescue
    const float pm = pmaxG[(size_t)row * NTILE + lane];  // lanes 0..63 = all tiles
    const float ps = psumG[(size_t)row * NTILE + lane];
    float m = pm, s = ps;
#pragma unroll
    for (int o = 1; o < 64; o <<= 1) {
      m = fmaxf(m, __shfl_xor(m, o));
      s += __shfl_xor(s, o);
    }
    const float thr = m - TAU;
    unsigned long long tmask = __ballot(pm >= thr);  // candidate tiles (~1)
    float bestv = -1e30f;
    int   besti = 0x7fffffff;
    const float4* xr4 = (const float4*)(xf + (size_t)row * D_);
    while (tmask) {
      const int t = __ffsll(tmask) - 1;
      tmask &= tmask - 1;
      const float* Lr = logits + (size_t)row * V_ + t * 128;
      const float l0 = Lr[lane], l1 = Lr[lane + 64];
      unsigned long long c0 = __ballot(l0 >= thr);
      unsigned long long c1 = __ballot(l1 >= thr);
      while (c0 | c1) {
        int col;
        if (c0) { const int j = __ffsll(c0) - 1; c0 &= c0 - 1; col = t * 128 + j; }
        else    { const int j = __ffsll(c1) - 1; c1 &= c1 - 1; col = t * 128 + 64 + j; }
        // exact fp32 dot x[row] . w[col]
        const float4* wr4 = (const float4*)(wf + (size_t)col * D_);
        float p = 0.f;
#pragma unroll
        for (int j = 0; j < 2; ++j) {
          const float4 a = xr4[lane + 64 * j];
          const float4 b = wr4[lane + 64 * j];
          p += a.x * b.x + a.y * b.y + a.z * b.z + a.w * b.w;
        }
#pragma unroll
        for (int o = 1; o < 64; o <<= 1) p += __shfl_xor(p, o);
        const float tot = p + bias[col];
        if (tot > bestv || (tot == bestv && col < besti)) { bestv = tot; besti = col; }
      }
    }
    if (lane == 0) {
      tokf[row] = (float)besti;
      sinv_s = 1.0f / s;
    }
  }
  __syncthreads();
  const float si = sinv_s;

  // softmax sweep: region bases are ==1 (mod 4) floats -> 3-head + float4 body + 1-tail
  const float* L = logits + (size_t)row * V_;
  float*       S = soft   + (size_t)row * V_;
  if (tid < 3)  S[tid]  = __expf(L[tid]) * si;
  if (tid == 3) S[8191] = __expf(L[8191]) * si;
  const float4* L4 = (const float4*)(L + 3);
  float4*       S4 = (float4*)(S + 3);
  for (int i = tid; i < 2047; i += 256) {
    const float4 v = L4[i];
    float4 o;
    o.x = __expf(v.x) * si; o.y = __expf(v.y) * si;
    o.z = __expf(v.z) * si; o.w = __expf(v.w) * si;
    S4[i] = o;
  }
}

// ---------------- pass 3: quantized gather + commitment loss ----------------
__global__ __launch_bounds__(256) void finalize_k(const float* __restrict__ tokf,
                                                  const float* __restrict__ cb,
                                                  const float* __restrict__ xf,
                                                  float* __restrict__ q,
                                                  float* __restrict__ loss) {
  const int row  = blockIdx.x * 4 + (threadIdx.x >> 6);  // one wave per row
  const int lane = threadIdx.x & 63;
  const int idx  = (int)tokf[row];
  const float4* cr = (const float4*)(cb + (size_t)idx * D_);
  const float4* xr = (const float4*)(xf + (size_t)row * D_);
  float4* qr = (float4*)(q + (size_t)row * D_);
  float ls = 0.f;
#pragma unroll
  for (int j = 0; j < 2; ++j) {
    const int c = lane + j * 64;
    const float4 cv = cr[c];
    const float4 xv = xr[c];
    qr[c] = cv;
    const float dx = cv.x - xv.x, dy = cv.y - xv.y, dz = cv.z - xv.z, dw = cv.w - xv.w;
    ls += dx * dx + dy * dy + dz * dz + dw * dw;
  }
#pragma unroll
  for (int o = 32; o; o >>= 1) ls += __shfl_xor(ls, o);
  if (lane == 0) atomicAdd(loss, ls * (1.0f / 4194304.0f));
}

extern "C" void kernel_launch(void* const* d_in, const int* in_sizes, int n_in,
                              void* d_out, int out_size, void* d_ws, size_t ws_size,
                              hipStream_t stream) {
  const float* x  = (const float*)d_in[0];  // inputs   [8192][512]
  const float* cb = (const float*)d_in[1];  // codebook [8192][512]
  const float* wl = (const float*)d_in[2];  // W_logits [8192][512]
  const float* bl = (const float*)d_in[3];  // b_logits [8192]
  float* out = (float*)d_out;

  float* qout   = out + OFF_Q;
  float* tokf   = out + OFF_TOK;
  float* loss   = out + OFF_LOSS;
  float* soft   = out + OFF_SOFT;
  float* logits = out + OFF_LOGITS;

  // scratch carved from output regions (each rewritten later in the pipeline):
  unsigned short* Abf = (unsigned short*)(out + STAGE_F);  // in soft region
  unsigned short* Wbf = Abf + (size_t)BT_ * D_;
  float* pmaxG = qout;            // [8192][64] in quantized region
  float* psumG = qout + 524288;   // [8192][64]

  hipMemsetAsync(loss, 0, 4, stream);

  to_bf16_k<<<2048, 256, 0, stream>>>((const float4*)x, (const float4*)wl,
                                      (u16x4*)Abf, (u16x4*)Wbf);
  gemm_logits<<<dim3(64, 64), 256, 0, stream>>>(Abf, Wbf, bl, logits, pmaxG, psumG);
  row_finish<<<8192, 256, 0, stream>>>(logits, pmaxG, psumG, x, wl, bl, tokf, soft);
  finalize_k<<<2048, 256, 0, stream>>>(tokf, cb, x, qout, loss);
}

// Round 3
// 414.658 us; speedup vs baseline: 1.4060x; 1.0457x over previous
//
#include <hip/hip_runtime.h>
#include <hip/hip_bf16.h>

#define BT_ 8192   // B*T
#define D_  512
#define V_  8192
#define NTILE 64   // V / 128 col-tiles

// d_out float offsets (outputs concatenated in return order)
#define OFF_Q      0
#define OFF_TOK    4194304
#define OFF_LOSS   4202496
#define OFF_SOFT   4202497
#define OFF_LOGITS 71311361
// bf16 staging scratch inside soft region, 16B-aligned float offset
#define STAGE_F    4202500

#define TAU  0.02f

typedef __attribute__((ext_vector_type(8))) short bf16x8;
typedef __attribute__((ext_vector_type(4))) float f32x4;
typedef __attribute__((ext_vector_type(4))) unsigned short u16x4;

__device__ __forceinline__ unsigned short bf16rne(float f) {
  unsigned int u = __float_as_uint(f);
  return (unsigned short)((u + 0x7fffu + ((u >> 16) & 1u)) >> 16);
}

// ---------------- pass 0: fp32 -> bf16 for X and W (block-uniform source) ----------------
__global__ __launch_bounds__(256) void to_bf16_k(const float4* __restrict__ x,
                                                 const float4* __restrict__ w,
                                                 u16x4* __restrict__ xa,
                                                 u16x4* __restrict__ wb) {
  const int n4 = (BT_ * D_) / 4;          // 1048576 float4 per tensor
  const int half = gridDim.x >> 1;
  const bool isw = blockIdx.x >= half;    // block-uniform -> single load path
  const float4* __restrict__ s = isw ? w : x;
  u16x4* __restrict__ d = isw ? wb : xa;
  const int b0 = isw ? blockIdx.x - half : blockIdx.x;
  for (int i = b0 * 256 + threadIdx.x; i < n4; i += half * 256) {
    const float4 v = s[i];
    u16x4 o;
    o[0] = bf16rne(v.x); o[1] = bf16rne(v.y);
    o[2] = bf16rne(v.z); o[3] = bf16rne(v.w);
    d[i] = o;
  }
}

// ---------------- pass 1: bf16 MFMA GEMM + per-tile row stats ----------------
__device__ __forceinline__ void gload_lds16(const void* g, void* l) {
  __builtin_amdgcn_global_load_lds((const __attribute__((address_space(1))) void*)g,
                                   (__attribute__((address_space(3))) void*)l,
                                   16, 0, 0);
}

__global__ __launch_bounds__(256) void gemm_logits(const unsigned short* __restrict__ A,
                                                   const unsigned short* __restrict__ B,
                                                   const float* __restrict__ bias,
                                                   float* __restrict__ C,
                                                   float* __restrict__ pmaxT,
                                                   float* __restrict__ psumT) {
  __shared__ unsigned short sA[128 * 64];  // 16 KB
  __shared__ unsigned short sB[128 * 64];  // 16 KB
  const int tid  = threadIdx.x;
  const int lane = tid & 63;
  const int wv   = tid >> 6;

  // XCD-chunked swizzle: 8 XCDs, each owns two 16x16 block-squares (A~2.1MB+B~2.1MB ~ L2)
  const int bid   = blockIdx.y * 64 + blockIdx.x;
  const int xcd   = bid & 7;
  const int local = bid >> 3;              // 0..511
  const int ry    = (xcd >> 1) * 16;
  const int rx    = (xcd & 1) * 32;
  const int sub   = local >> 8;            // two 16x16 squares per rect
  const int rem   = local & 255;
  const int by    = ry + (rem >> 4);
  const int bx    = rx + sub * 16 + (rem & 15);

  const int row0 = by * 128;
  const int col0 = bx * 128;
  const int wr = wv >> 1, wc = wv & 1;  // 2x2 wave grid, 64x64 per wave

  f32x4 acc[4][4] = {};

  const char* Abase = (const char*)A + (size_t)row0 * (D_ * 2);
  const char* Bbase = (const char*)B + (size_t)col0 * (D_ * 2);

  for (int k0 = 0; k0 < D_; k0 += 64) {
#pragma unroll
    for (int j = 0; j < 4; ++j) {
      const int lbase = j * 4096 + wv * 1024;       // wave-uniform LDS byte base
      const int ff = lbase + lane * 16;
      const int r  = ff >> 7;
      const int cb = ff & 127;
      const size_t goff = (size_t)r * (D_ * 2) + (size_t)(k0 * 2) + cb;
      gload_lds16(Abase + goff, (char*)sA + lbase);
      gload_lds16(Bbase + goff, (char*)sB + lbase);
    }
    __syncthreads();
#pragma unroll
    for (int kk = 0; kk < 64; kk += 32) {
      const int koff = kk + 8 * (lane >> 4);
      bf16x8 af[4], bfr[4];
#pragma unroll
      for (int m = 0; m < 4; ++m)
        af[m] = *(const bf16x8*)(sA + (wr * 64 + m * 16 + (lane & 15)) * 64 + koff);
#pragma unroll
      for (int n = 0; n < 4; ++n)
        bfr[n] = *(const bf16x8*)(sB + (wc * 64 + n * 16 + (lane & 15)) * 64 + koff);
#pragma unroll
      for (int m = 0; m < 4; ++m)
#pragma unroll
        for (int n = 0; n < 4; ++n)
          acc[m][n] = __builtin_amdgcn_mfma_f32_16x16x32_bf16(af[m], bfr[n], acc[m][n], 0, 0, 0);
    }
    __syncthreads();   // also guards sA reuse as stats scratch below
  }

  // epilogue: write C, accumulate per-row {max, sum(exp)} over this block's 128 cols
  float* pmS = (float*)sA;        // [2][128] max   (sA free after last barrier)
  float* psS = pmS + 256;         // [2][128] sumexp

  const int gcol = col0 + wc * 64 + (lane & 15);
  float bv[4];
#pragma unroll
  for (int n = 0; n < 4; ++n) bv[n] = bias[gcol + n * 16];

#pragma unroll
  for (int m = 0; m < 4; ++m) {
    const int rib0 = wr * 64 + m * 16 + 4 * (lane >> 4);
#pragma unroll
    for (int r = 0; r < 4; ++r) {
      const size_t rowg = row0 + rib0 + r;
      float vmx = -1e30f, vsm = 0.f;
#pragma unroll
      for (int n = 0; n < 4; ++n) {
        const float v = acc[m][n][r] + bv[n];
        C[rowg * V_ + gcol + n * 16] = v;
        vmx = fmaxf(vmx, v);
        vsm += __expf(v);
      }
#pragma unroll
      for (int o = 1; o < 16; o <<= 1) {   // reduce across the 16-lane col group
        vmx = fmaxf(vmx, __shfl_xor(vmx, o));
        vsm += __shfl_xor(vsm, o);
      }
      if ((lane & 15) == 0) {
        pmS[wc * 128 + rib0 + r] = vmx;
        psS[wc * 128 + rib0 + r] = vsm;
      }
    }
  }
  __syncthreads();
  if (tid < 128) {
    const float mx = fmaxf(pmS[tid], pmS[128 + tid]);
    const float sm = psS[tid] + psS[128 + tid];
    // transposed [tile][row] layout: contiguous 512B per block, block-exclusive lines
    pmaxT[(size_t)bx * BT_ + row0 + tid] = mx;
    psumT[(size_t)bx * BT_ + row0 + tid] = sm;
  }
}

// ---- pass 2: per-row reduce partials, exact-fp32 argmax rescue, softmax sweep ----
// barrier-free: every wave reduces the 64 tile-partials itself (L2-hot, 512B)
__global__ __launch_bounds__(256) void row_finish(const float* __restrict__ logits,
                                                  const float* __restrict__ pmaxT,
                                                  const float* __restrict__ psumT,
                                                  const float* __restrict__ xf,
                                                  const float* __restrict__ wf,
                                                  const float* __restrict__ bias,
                                                  float* __restrict__ tokf,
                                                  float* __restrict__ soft) {
  const int row  = blockIdx.x;
  const int tid  = threadIdx.x;
  const int lane = tid & 63;
  const int wv   = tid >> 6;

  const float pm = pmaxT[(size_t)lane * BT_ + row];  // lane = tile index
  const float ps = psumT[(size_t)lane * BT_ + row];
  float m = pm, s = ps;
#pragma unroll
  for (int o = 1; o < 64; o <<= 1) {
    m = fmaxf(m, __shfl_xor(m, o));
    s += __shfl_xor(s, o);
  }
  const float si = 1.0f / s;

  const float* L = logits + (size_t)row * V_;
  float*       S = soft   + (size_t)row * V_;
  const float4* L4 = (const float4*)(L + 3);  // region base ==1 mod 4 -> +3 is 16B-aligned
  float4*       S4 = (float4*)(S + 3);

  if (wv == 0) {
    // ---- argmax rescue on wave 0 ----
    const float thr = m - TAU;
    unsigned long long tmask = __ballot(pm >= thr);  // candidate tiles (~1)
    float bestv = -1e30f;
    int   besti = 0x7fffffff;
    const float4* xr4 = (const float4*)(xf + (size_t)row * D_);
    while (tmask) {
      const int t = __ffsll(tmask) - 1;
      tmask &= tmask - 1;
      const float* Lr = L + t * 128;
      const float l0 = Lr[lane], l1 = Lr[lane + 64];
      unsigned long long c0 = __ballot(l0 >= thr);
      unsigned long long c1 = __ballot(l1 >= thr);
      while (c0 | c1) {
        int col;
        if (c0) { const int j = __ffsll(c0) - 1; c0 &= c0 - 1; col = t * 128 + j; }
        else    { const int j = __ffsll(c1) - 1; c1 &= c1 - 1; col = t * 128 + 64 + j; }
        const float4* wr4 = (const float4*)(wf + (size_t)col * D_);
        float p = 0.f;
#pragma unroll
        for (int j = 0; j < 2; ++j) {
          const float4 a = xr4[lane + 64 * j];
          const float4 b = wr4[lane + 64 * j];
          p += a.x * b.x + a.y * b.y + a.z * b.z + a.w * b.w;
        }
#pragma unroll
        for (int o = 1; o < 64; o <<= 1) p += __shfl_xor(p, o);
        const float tot = p + bias[col];
        if (tot > bestv || (tot == bestv && col < besti)) { bestv = tot; besti = col; }
      }
    }
    if (lane == 0) tokf[row] = (float)besti;
    // wave0's small static sweep share + head/tail
    if (lane < 3)  S[lane]  = __expf(L[lane]) * si;
    if (lane == 3) S[8191] = __expf(L[8191]) * si;
#pragma unroll
    for (int k = 0; k < 2; ++k) {
      const int i = 1920 + k * 64 + lane;
      if (i < 2047) {
        const float4 v = L4[i];
        float4 o;
        o.x = __expf(v.x) * si; o.y = __expf(v.y) * si;
        o.z = __expf(v.z) * si; o.w = __expf(v.w) * si;
        S4[i] = o;
      }
    }
  } else {
    // waves 1-3: bulk sweep [0, 1920) immediately, no barrier
    const int t = tid - 64;  // 0..191
#pragma unroll
    for (int k = 0; k < 10; ++k) {
      const int i = k * 192 + t;
      const float4 v = L4[i];
      float4 o;
      o.x = __expf(v.x) * si; o.y = __expf(v.y) * si;
      o.z = __expf(v.z) * si; o.w = __expf(v.w) * si;
      S4[i] = o;
    }
  }
}

// ---------------- pass 3: quantized gather + commitment loss ----------------
__global__ __launch_bounds__(256) void finalize_k(const float* __restrict__ tokf,
                                                  const float* __restrict__ cb,
                                                  const float* __restrict__ xf,
                                                  float* __restrict__ q,
                                                  float* __restrict__ loss) {
  const int row  = blockIdx.x * 4 + (threadIdx.x >> 6);  // one wave per row
  const int lane = threadIdx.x & 63;
  const int idx  = (int)tokf[row];
  const float4* cr = (const float4*)(cb + (size_t)idx * D_);
  const float4* xr = (const float4*)(xf + (size_t)row * D_);
  float4* qr = (float4*)(q + (size_t)row * D_);
  float ls = 0.f;
#pragma unroll
  for (int j = 0; j < 2; ++j) {
    const int c = lane + j * 64;
    const float4 cv = cr[c];
    const float4 xv = xr[c];
    qr[c] = cv;
    const float dx = cv.x - xv.x, dy = cv.y - xv.y, dz = cv.z - xv.z, dw = cv.w - xv.w;
    ls += dx * dx + dy * dy + dz * dz + dw * dw;
  }
#pragma unroll
  for (int o = 32; o; o >>= 1) ls += __shfl_xor(ls, o);
  if (lane == 0) atomicAdd(loss, ls * (1.0f / 4194304.0f));
}

extern "C" void kernel_launch(void* const* d_in, const int* in_sizes, int n_in,
                              void* d_out, int out_size, void* d_ws, size_t ws_size,
                              hipStream_t stream) {
  const float* x  = (const float*)d_in[0];  // inputs   [8192][512]
  const float* cb = (const float*)d_in[1];  // codebook [8192][512]
  const float* wl = (const float*)d_in[2];  // W_logits [8192][512]
  const float* bl = (const float*)d_in[3];  // b_logits [8192]
  float* out = (float*)d_out;

  float* qout   = out + OFF_Q;
  float* tokf   = out + OFF_TOK;
  float* loss   = out + OFF_LOSS;
  float* soft   = out + OFF_SOFT;
  float* logits = out + OFF_LOGITS;

  // scratch carved from output regions (each rewritten later in the pipeline):
  unsigned short* Abf = (unsigned short*)(out + STAGE_F);  // in soft region
  unsigned short* Wbf = Abf + (size_t)BT_ * D_;
  float* pmaxT = qout;            // [64][8192] in quantized region (finalize overwrites last)
  float* psumT = qout + 524288;   // [64][8192]

  hipMemsetAsync(loss, 0, 4, stream);

  to_bf16_k<<<2048, 256, 0, stream>>>((const float4*)x, (const float4*)wl,
                                      (u16x4*)Abf, (u16x4*)Wbf);
  gemm_logits<<<dim3(64, 64), 256, 0, stream>>>(Abf, Wbf, bl, logits, pmaxT, psumT);
  row_finish<<<8192, 256, 0, stream>>>(logits, pmaxT, psumT, x, wl, bl, tokf, soft);
  finalize_k<<<2048, 256, 0, stream>>>(tokf, cb, x, qout, loss);
}

// Round 4
// 374.503 us; speedup vs baseline: 1.5568x; 1.1072x over previous
//
#include <hip/hip_runtime.h>
#include <hip/hip_bf16.h>

#define BT_ 8192   // B*T
#define D_  512
#define V_  8192
#define NT2 32     // V / 256 col-tiles

// d_out float offsets (outputs concatenated in return order)
#define OFF_Q      0
#define OFF_TOK    4194304
#define OFF_LOSS   4202496
#define OFF_SOFT   4202497
#define OFF_LOGITS 71311361
#define STAGE_F    4202500   // bf16 staging scratch inside soft region (16B-aligned)

#define TAU  0.02f

typedef __attribute__((ext_vector_type(8))) short bf16x8;
typedef __attribute__((ext_vector_type(4))) float f32x4;
typedef __attribute__((ext_vector_type(4))) unsigned short u16x4;

__device__ __forceinline__ unsigned short bf16rne(float f) {
  unsigned int u = __float_as_uint(f);
  return (unsigned short)((u + 0x7fffu + ((u >> 16) & 1u)) >> 16);
}

// ---------------- pass 0: fp32 -> bf16 for X and W (block-uniform source) ----------------
__global__ __launch_bounds__(256) void to_bf16_k(const float4* __restrict__ x,
                                                 const float4* __restrict__ w,
                                                 u16x4* __restrict__ xa,
                                                 u16x4* __restrict__ wb) {
  const int n4 = (BT_ * D_) / 4;
  const int half = gridDim.x >> 1;
  const bool isw = blockIdx.x >= half;
  const float4* __restrict__ s = isw ? w : x;
  u16x4* __restrict__ d = isw ? wb : xa;
  const int b0 = isw ? blockIdx.x - half : blockIdx.x;
  for (int i = b0 * 256 + threadIdx.x; i < n4; i += half * 256) {
    const float4 v = s[i];
    u16x4 o;
    o[0] = bf16rne(v.x); o[1] = bf16rne(v.y);
    o[2] = bf16rne(v.z); o[3] = bf16rne(v.w);
    d[i] = o;
  }
}

// ---------------- pass 1: 256x256 8-phase bf16 MFMA GEMM + per-tile row stats ----------------
__device__ __forceinline__ void gload_lds16(const void* g, void* l) {
  __builtin_amdgcn_global_load_lds((const __attribute__((address_space(1))) void*)g,
                                   (__attribute__((address_space(3))) void*)l,
                                   16, 0, 0);
}

// raw barrier + compiler memory fence (no vmcnt/lgkm drain)
__device__ __forceinline__ void barf() {
  __builtin_amdgcn_s_barrier();
  asm volatile("" ::: "memory");
}
__device__ __forceinline__ void vmcnt2() { asm volatile("s_waitcnt vmcnt(2)" ::: "memory"); }
__device__ __forceinline__ void vmcnt0() { asm volatile("s_waitcnt vmcnt(0)" ::: "memory"); }

// stage one half-tile (16 KB = 2 issues x 512 lanes x 16B) of K-tile `ktile`.
// LDS dest linear; global source inverse-st_16x32-swizzled (T2 both-sides rule).
__device__ __forceinline__ void stage_unit(const char* __restrict__ tb, char* ldsRegion,
                                           int ktile, int half, int wid, int lane) {
#pragma unroll
  for (int issue = 0; issue < 2; ++issue) {
    const int d = half * 16384 + issue * 8192 + wid * 1024 + lane * 16;
    const int l = d ^ (((d >> 9) & 1) << 5);
    gload_lds16(tb + (size_t)(l >> 7) * 1024 + ktile * 128 + (l & 127),
                ldsRegion + half * 16384 + issue * 8192 + wid * 1024);
  }
}

// swizzled fragment read: logical (row R, k-bytes ks*64 + 16*g), XOR bit5 by R bit2
__device__ __forceinline__ bf16x8 rdfrag(const char* base, int R, int ks, int g) {
  return *(const bf16x8*)(base + R * 128 + ((ks * 64 + 16 * g) ^ (((R >> 2) & 1) << 5)));
}

__device__ __forceinline__ void kgroup(int t, int smode, char* lds,
                                       const char* __restrict__ Ab,
                                       const char* __restrict__ Bb,
                                       int wr, int wc, int lane, int wid,
                                       f32x4 (&acc)[8][4]) {
  char* aL = lds + (t & 1) * 32768;
  char* bL = lds + 65536 + (t & 1) * 32768;
  char* aS = lds + ((t & 1) ^ 1) * 32768;
  char* bS = lds + 65536 + ((t & 1) ^ 1) * 32768;
  const int cg = lane & 15, g = lane >> 4;
  bf16x8 a[4][2], b0[2][2], b1[2][2];

  // ---- phase 1: read A01 + B01 of t; stage (t+1).A-half1
#pragma unroll
  for (int m = 0; m < 4; ++m)
#pragma unroll
    for (int ks = 0; ks < 2; ++ks)
      a[m][ks] = rdfrag(aL, wr * 128 + m * 16 + cg, ks, g);
#pragma unroll
  for (int n = 0; n < 2; ++n)
#pragma unroll
    for (int ks = 0; ks < 2; ++ks)
      b0[n][ks] = rdfrag(bL, wc * 64 + n * 16 + cg, ks, g);
  if (smode >= 1) stage_unit(Ab, aS, t + 1, 1, wid, lane);
  barf();
  __builtin_amdgcn_s_setprio(1);
#pragma unroll
  for (int m = 0; m < 4; ++m)
#pragma unroll
    for (int n = 0; n < 2; ++n)
#pragma unroll
      for (int ks = 0; ks < 2; ++ks)
        acc[m][n] = __builtin_amdgcn_mfma_f32_16x16x32_bf16(a[m][ks], b0[n][ks], acc[m][n], 0, 0, 0);
  __builtin_amdgcn_s_setprio(0);
  barf();

  // ---- phase 2: read B23 of t; stage (t+1).B-half0
#pragma unroll
  for (int n = 0; n < 2; ++n)
#pragma unroll
    for (int ks = 0; ks < 2; ++ks)
      b1[n][ks] = rdfrag(bL, wc * 64 + (n + 2) * 16 + cg, ks, g);
  if (smode >= 1) stage_unit(Bb, bS, t + 1, 0, wid, lane);
  barf();
  __builtin_amdgcn_s_setprio(1);
#pragma unroll
  for (int m = 0; m < 4; ++m)
#pragma unroll
    for (int n = 0; n < 2; ++n)
#pragma unroll
      for (int ks = 0; ks < 2; ++ks)
        acc[m][n + 2] = __builtin_amdgcn_mfma_f32_16x16x32_bf16(a[m][ks], b1[n][ks], acc[m][n + 2], 0, 0, 0);
  __builtin_amdgcn_s_setprio(0);
  barf();

  // ---- phase 3: read A23 of t (overwrite a); stage (t+1).B-half1
#pragma unroll
  for (int m = 0; m < 4; ++m)
#pragma unroll
    for (int ks = 0; ks < 2; ++ks)
      a[m][ks] = rdfrag(aL, wr * 128 + (m + 4) * 16 + cg, ks, g);
  if (smode >= 1) stage_unit(Bb, bS, t + 1, 1, wid, lane);
  barf();
  __builtin_amdgcn_s_setprio(1);
#pragma unroll
  for (int m = 0; m < 4; ++m)
#pragma unroll
    for (int n = 0; n < 2; ++n)
#pragma unroll
      for (int ks = 0; ks < 2; ++ks)
        acc[m + 4][n + 2] = __builtin_amdgcn_mfma_f32_16x16x32_bf16(a[m][ks], b1[n][ks], acc[m + 4][n + 2], 0, 0, 0);
  __builtin_amdgcn_s_setprio(0);
  barf();

  // ---- phase 4: MFMA A23 x B01 (regs only); stage (t+2).A-half0 into read-parity buf
  if (smode == 2) stage_unit(Ab, aL, t + 2, 0, wid, lane);  // safe: all t-reads retired by ph3
  barf();
  __builtin_amdgcn_s_setprio(1);
#pragma unroll
  for (int m = 0; m < 4; ++m)
#pragma unroll
    for (int n = 0; n < 2; ++n)
#pragma unroll
      for (int ks = 0; ks < 2; ++ks)
        acc[m + 4][n] = __builtin_amdgcn_mfma_f32_16x16x32_bf16(a[m][ks], b0[n][ks], acc[m + 4][n], 0, 0, 0);
  __builtin_amdgcn_s_setprio(0);
  if (smode == 2) vmcnt2();        // ledger: only (t+2).A0 (2 loads) may stay in flight
  else if (smode == 1) vmcnt0();   // tail: tile7 fully staged, nothing younger
  barf();
}

__global__ __launch_bounds__(512, 2) void gemm8(const unsigned short* __restrict__ A,
                                                const unsigned short* __restrict__ B,
                                                const float* __restrict__ bias,
                                                float* __restrict__ C,
                                                float* __restrict__ pmaxT,
                                                float* __restrict__ psumT) {
  __shared__ char lds[131072];  // A dbuf 64K | B dbuf 64K
  const int tid  = threadIdx.x;
  const int lane = tid & 63;
  const int wid  = tid >> 6;           // 8 waves: 2M x 4N
  const int wr   = wid >> 2, wc = wid & 3;

  // bijective XCD chunking over the 32x32 block grid (8x16 blocks per XCD)
  const int bid = blockIdx.x;
  const int xcd = bid & 7;
  const int s   = bid >> 3;
  const int by  = (xcd >> 1) * 8 + (s >> 4);
  const int bx  = (xcd & 1) * 16 + (s & 15);
  const int row0 = by * 256, col0 = bx * 256;

  const char* Ab = (const char*)A + (size_t)row0 * 1024;
  const char* Bb = (const char*)B + (size_t)col0 * 1024;

  f32x4 acc[8][4] = {};

  // prologue: stage tile0 fully + tile1.A-half0; wait tile0 (2 younger in flight)
  stage_unit(Ab, lds, 0, 0, wid, lane);
  stage_unit(Ab, lds, 0, 1, wid, lane);
  stage_unit(Bb, lds + 65536, 0, 0, wid, lane);
  stage_unit(Bb, lds + 65536, 0, 1, wid, lane);
  stage_unit(Ab, lds + 32768, 1, 0, wid, lane);
  vmcnt2();
  barf();

  for (int t = 0; t < 6; ++t)
    kgroup(t, 2, lds, Ab, Bb, wr, wc, lane, wid, acc);
  kgroup(6, 1, lds, Ab, Bb, wr, wc, lane, wid, acc);
  kgroup(7, 0, lds, Ab, Bb, wr, wc, lane, wid, acc);

  // ---- epilogue: C-write + per-row {max, sumexp} over this block's 256 cols ----
  float* pmS = (float*)lds;           // [4][256]
  float* psS = (float*)lds + 1024;    // [4][256]
  const int cg = lane & 15, g = lane >> 4;

  float bv[4];
#pragma unroll
  for (int n = 0; n < 4; ++n) bv[n] = bias[col0 + wc * 64 + n * 16 + cg];

#pragma unroll
  for (int m = 0; m < 8; ++m) {
#pragma unroll
    for (int rr = 0; rr < 4; ++rr) {
      const int R = wr * 128 + m * 16 + 4 * g + rr;
      const size_t rowg = row0 + R;
      float vmx = -1e30f, vsm = 0.f;
#pragma unroll
      for (int n = 0; n < 4; ++n) {
        const float v = acc[m][n][rr] + bv[n];
        C[rowg * V_ + col0 + wc * 64 + n * 16 + cg] = v;
        vmx = fmaxf(vmx, v);
        vsm += __expf(v);
      }
#pragma unroll
      for (int o = 1; o < 16; o <<= 1) {
        vmx = fmaxf(vmx, __shfl_xor(vmx, o));
        vsm += __shfl_xor(vsm, o);
      }
      if (cg == 0) { pmS[wc * 256 + R] = vmx; psS[wc * 256 + R] = vsm; }
    }
  }
  __syncthreads();
  if (tid < 256) {
    float mx = fmaxf(fmaxf(pmS[tid], pmS[256 + tid]), fmaxf(pmS[512 + tid], pmS[768 + tid]));
    float sm = psS[tid] + psS[256 + tid] + psS[512 + tid] + psS[768 + tid];
    pmaxT[(size_t)bx * BT_ + row0 + tid] = mx;
    psumT[(size_t)bx * BT_ + row0 + tid] = sm;
  }
}

// ---- pass 2: per-row reduce partials, exact-fp32 argmax rescue, softmax sweep ----
__global__ __launch_bounds__(256) void row_finish(const float* __restrict__ logits,
                                                  const float* __restrict__ pmaxT,
                                                  const float* __restrict__ psumT,
                                                  const float* __restrict__ xf,
                                                  const float* __restrict__ wf,
                                                  const float* __restrict__ bias,
                                                  float* __restrict__ tokf,
                                                  float* __restrict__ soft) {
  const int row  = blockIdx.x;
  const int tid  = threadIdx.x;
  const int lane = tid & 63;
  const int wv   = tid >> 6;

  const int tl = lane & 31;                          // tile index (dup in high lanes)
  const float pm = pmaxT[(size_t)tl * BT_ + row];
  const float ps = psumT[(size_t)tl * BT_ + row];
  float m = pm, s = ps;
#pragma unroll
  for (int o = 1; o < 32; o <<= 1) {
    m = fmaxf(m, __shfl_xor(m, o));
    s += __shfl_xor(s, o);
  }
  const float si = 1.0f / s;

  const float* L = logits + (size_t)row * V_;
  float*       S = soft   + (size_t)row * V_;
  const float4* L4 = (const float4*)(L + 3);  // region base ==1 mod 4 -> +3 is 16B-aligned
  float4*       S4 = (float4*)(S + 3);

  if (wv == 0) {
    // ---- argmax rescue on wave 0 ----
    const float thr = m - TAU;
    unsigned long long tmask = __ballot(pm >= thr) & 0xFFFFFFFFull;
    float bestv = -1e30f;
    int   besti = 0x7fffffff;
    const float4* xr4 = (const float4*)(xf + (size_t)row * D_);
    while (tmask) {
      const int t = __ffsll(tmask) - 1;
      tmask &= tmask - 1;
      const float* Lr = L + t * 256;
#pragma unroll
      for (int kq = 0; kq < 4; ++kq) {
        const float lv = Lr[kq * 64 + lane];
        unsigned long long c = __ballot(lv >= thr);
        while (c) {
          const int j = __ffsll(c) - 1;
          c &= c - 1;
          const int col = t * 256 + kq * 64 + j;
          const float4* wr4 = (const float4*)(wf + (size_t)col * D_);
          float p = 0.f;
#pragma unroll
          for (int q = 0; q < 2; ++q) {
            const float4 av = xr4[lane + 64 * q];
            const float4 bvv = wr4[lane + 64 * q];
            p += av.x * bvv.x + av.y * bvv.y + av.z * bvv.z + av.w * bvv.w;
          }
#pragma unroll
          for (int o = 1; o < 64; o <<= 1) p += __shfl_xor(p, o);
          const float tot = p + bias[col];
          if (tot > bestv || (tot == bestv && col < besti)) { bestv = tot; besti = col; }
        }
      }
    }
    if (lane == 0) tokf[row] = (float)besti;
    // wave0's small static sweep share + head/tail
    if (lane < 3)  S[lane] = __expf(L[lane]) * si;
    if (lane == 3) S[8191] = __expf(L[8191]) * si;
#pragma unroll
    for (int k = 0; k < 2; ++k) {
      const int i = 1920 + k * 64 + lane;
      if (i < 2047) {
        const float4 v = L4[i];
        float4 o;
        o.x = __expf(v.x) * si; o.y = __expf(v.y) * si;
        o.z = __expf(v.z) * si; o.w = __expf(v.w) * si;
        S4[i] = o;
      }
    }
  } else {
    // waves 1-3: bulk sweep [0, 1920) immediately, no barrier
    const int t = tid - 64;  // 0..191
#pragma unroll
    for (int k = 0; k < 10; ++k) {
      const int i = k * 192 + t;
      const float4 v = L4[i];
      float4 o;
      o.x = __expf(v.x) * si; o.y = __expf(v.y) * si;
      o.z = __expf(v.z) * si; o.w = __expf(v.w) * si;
      S4[i] = o;
    }
  }
}

// ---------------- pass 3: quantized gather + commitment loss ----------------
__global__ __launch_bounds__(256) void finalize_k(const float* __restrict__ tokf,
                                                  const float* __restrict__ cb,
                                                  const float* __restrict__ xf,
                                                  float* __restrict__ q,
                                                  float* __restrict__ loss) {
  const int row  = blockIdx.x * 4 + (threadIdx.x >> 6);
  const int lane = threadIdx.x & 63;
  const int idx  = (int)tokf[row];
  const float4* cr = (const float4*)(cb + (size_t)idx * D_);
  const float4* xr = (const float4*)(xf + (size_t)row * D_);
  float4* qr = (float4*)(q + (size_t)row * D_);
  float ls = 0.f;
#pragma unroll
  for (int j = 0; j < 2; ++j) {
    const int c = lane + j * 64;
    const float4 cv = cr[c];
    const float4 xv = xr[c];
    qr[c] = cv;
    const float dx = cv.x - xv.x, dy = cv.y - xv.y, dz = cv.z - xv.z, dw = cv.w - xv.w;
    ls += dx * dx + dy * dy + dz * dz + dw * dw;
  }
#pragma unroll
  for (int o = 32; o; o >>= 1) ls += __shfl_xor(ls, o);
  if (lane == 0) atomicAdd(loss, ls * (1.0f / 4194304.0f));
}

extern "C" void kernel_launch(void* const* d_in, const int* in_sizes, int n_in,
                              void* d_out, int out_size, void* d_ws, size_t ws_size,
                              hipStream_t stream) {
  const float* x  = (const float*)d_in[0];  // inputs   [8192][512]
  const float* cb = (const float*)d_in[1];  // codebook [8192][512]
  const float* wl = (const float*)d_in[2];  // W_logits [8192][512]
  const float* bl = (const float*)d_in[3];  // b_logits [8192]
  float* out = (float*)d_out;

  float* qout   = out + OFF_Q;
  float* tokf   = out + OFF_TOK;
  float* loss   = out + OFF_LOSS;
  float* soft   = out + OFF_SOFT;
  float* logits = out + OFF_LOGITS;

  // scratch carved from output regions (each rewritten later in the pipeline):
  unsigned short* Abf = (unsigned short*)(out + STAGE_F);  // in soft region
  unsigned short* Wbf = Abf + (size_t)BT_ * D_;
  float* pmaxT = qout;            // [32][8192] in quantized region (finalize overwrites last)
  float* psumT = qout + 262144;   // [32][8192]

  hipMemsetAsync(loss, 0, 4, stream);

  to_bf16_k<<<2048, 256, 0, stream>>>((const float4*)x, (const float4*)wl,
                                      (u16x4*)Abf, (u16x4*)Wbf);
  gemm8<<<1024, 512, 0, stream>>>(Abf, Wbf, bl, logits, pmaxT, psumT);
  row_finish<<<8192, 256, 0, stream>>>(logits, pmaxT, psumT, x, wl, bl, tokf, soft);
  finalize_k<<<2048, 256, 0, stream>>>(tokf, cb, x, qout, loss);
}

// Round 5
// 372.975 us; speedup vs baseline: 1.5632x; 1.0041x over previous
//
#include <hip/hip_runtime.h>
#include <hip/hip_bf16.h>

#define BT_ 8192   // B*T
#define D_  512
#define V_  8192
#define NT2 32     // V / 256 col-tiles

// d_out float offsets (outputs concatenated in return order)
#define OFF_Q      0
#define OFF_TOK    4194304
#define OFF_LOSS   4202496
#define OFF_SOFT   4202497
#define OFF_LOGITS 71311361
#define STAGE_F    4202500   // bf16 staging scratch inside soft region (16B-aligned)

#define TAU  0.02f

typedef __attribute__((ext_vector_type(8))) short bf16x8;
typedef __attribute__((ext_vector_type(4))) float f32x4;
typedef __attribute__((ext_vector_type(4))) unsigned short u16x4;

__device__ __forceinline__ unsigned short bf16rne(float f) {
  unsigned int u = __float_as_uint(f);
  return (unsigned short)((u + 0x7fffu + ((u >> 16) & 1u)) >> 16);
}

// ---------------- pass 0: fp32 -> bf16 for X and W (block-uniform source) ----------------
__global__ __launch_bounds__(256) void to_bf16_k(const float4* __restrict__ x,
                                                 const float4* __restrict__ w,
                                                 u16x4* __restrict__ xa,
                                                 u16x4* __restrict__ wb) {
  const int n4 = (BT_ * D_) / 4;
  const int half = gridDim.x >> 1;
  const bool isw = blockIdx.x >= half;
  const float4* __restrict__ s = isw ? w : x;
  u16x4* __restrict__ d = isw ? wb : xa;
  const int b0 = isw ? blockIdx.x - half : blockIdx.x;
  for (int i = b0 * 256 + threadIdx.x; i < n4; i += half * 256) {
    const float4 v = s[i];
    u16x4 o;
    o[0] = bf16rne(v.x); o[1] = bf16rne(v.y);
    o[2] = bf16rne(v.z); o[3] = bf16rne(v.w);
    d[i] = o;
  }
}

// ---------------- pass 1: 256x256 8-phase bf16 MFMA GEMM + per-tile row stats ----------------
__device__ __forceinline__ void gload_lds16(const void* g, void* l) {
  __builtin_amdgcn_global_load_lds((const __attribute__((address_space(1))) void*)g,
                                   (__attribute__((address_space(3))) void*)l,
                                   16, 0, 0);
}

// raw barrier + compiler memory fence (no vmcnt/lgkm drain)
__device__ __forceinline__ void barf() {
  __builtin_amdgcn_s_barrier();
  asm volatile("" ::: "memory");
}
__device__ __forceinline__ void vmcnt2() { asm volatile("s_waitcnt vmcnt(2)" ::: "memory"); }
__device__ __forceinline__ void vmcnt0() { asm volatile("s_waitcnt vmcnt(0)" ::: "memory"); }

// stage one half-tile (16 KB = 2 issues x 512 lanes x 16B) of K-tile `ktile`.
// LDS dest linear; global source inverse-swizzled (T2 both-sides rule).
// Swizzle: 3-bit XOR, addr ^= ((row&7)<<4) — involution, spreads 8 consecutive
// rows across the 8 16B-slots of a 128B line -> conflict-free ds_read_b128.
__device__ __forceinline__ void stage_unit(const char* __restrict__ tb, char* ldsRegion,
                                           int ktile, int half, int wid, int lane) {
#pragma unroll
  for (int issue = 0; issue < 2; ++issue) {
    const int d = half * 16384 + issue * 8192 + wid * 1024 + lane * 16;
    const int l = d ^ (((d >> 7) & 7) << 4);
    gload_lds16(tb + (size_t)(l >> 7) * 1024 + ktile * 128 + (l & 127),
                ldsRegion + half * 16384 + issue * 8192 + wid * 1024);
  }
}

// swizzled fragment read: logical (row R, k-bytes ks*64 + 16*g)
__device__ __forceinline__ bf16x8 rdfrag(const char* base, int R, int ks, int g) {
  return *(const bf16x8*)(base + R * 128 + ((ks * 64 + 16 * g) ^ ((R & 7) << 4)));
}

__device__ __forceinline__ void kgroup(int t, int smode, char* lds,
                                       const char* __restrict__ Ab,
                                       const char* __restrict__ Bb,
                                       int wr, int wc, int lane, int wid,
                                       f32x4 (&acc)[8][4]) {
  char* aL = lds + (t & 1) * 32768;
  char* bL = lds + 65536 + (t & 1) * 32768;
  char* aS = lds + ((t & 1) ^ 1) * 32768;
  char* bS = lds + 65536 + ((t & 1) ^ 1) * 32768;
  const int cg = lane & 15, g = lane >> 4;
  bf16x8 a[4][2], b0[2][2], b1[2][2];

  // ---- phase 1: read A01 + B01 of t; stage (t+1).A-half1
#pragma unroll
  for (int m = 0; m < 4; ++m)
#pragma unroll
    for (int ks = 0; ks < 2; ++ks)
      a[m][ks] = rdfrag(aL, wr * 128 + m * 16 + cg, ks, g);
#pragma unroll
  for (int n = 0; n < 2; ++n)
#pragma unroll
    for (int ks = 0; ks < 2; ++ks)
      b0[n][ks] = rdfrag(bL, wc * 64 + n * 16 + cg, ks, g);
  if (smode >= 1) stage_unit(Ab, aS, t + 1, 1, wid, lane);
  barf();
  __builtin_amdgcn_s_setprio(1);
#pragma unroll
  for (int m = 0; m < 4; ++m)
#pragma unroll
    for (int n = 0; n < 2; ++n)
#pragma unroll
      for (int ks = 0; ks < 2; ++ks)
        acc[m][n] = __builtin_amdgcn_mfma_f32_16x16x32_bf16(a[m][ks], b0[n][ks], acc[m][n], 0, 0, 0);
  __builtin_amdgcn_s_setprio(0);
  barf();

  // ---- phase 2: read B23 of t; stage (t+1).B-half0
#pragma unroll
  for (int n = 0; n < 2; ++n)
#pragma unroll
    for (int ks = 0; ks < 2; ++ks)
      b1[n][ks] = rdfrag(bL, wc * 64 + (n + 2) * 16 + cg, ks, g);
  if (smode >= 1) stage_unit(Bb, bS, t + 1, 0, wid, lane);
  barf();
  __builtin_amdgcn_s_setprio(1);
#pragma unroll
  for (int m = 0; m < 4; ++m)
#pragma unroll
    for (int n = 0; n < 2; ++n)
#pragma unroll
      for (int ks = 0; ks < 2; ++ks)
        acc[m][n + 2] = __builtin_amdgcn_mfma_f32_16x16x32_bf16(a[m][ks], b1[n][ks], acc[m][n + 2], 0, 0, 0);
  __builtin_amdgcn_s_setprio(0);
  barf();

  // ---- phase 3: read A23 of t (overwrite a); stage (t+1).B-half1
#pragma unroll
  for (int m = 0; m < 4; ++m)
#pragma unroll
    for (int ks = 0; ks < 2; ++ks)
      a[m][ks] = rdfrag(aL, wr * 128 + (m + 4) * 16 + cg, ks, g);
  if (smode >= 1) stage_unit(Bb, bS, t + 1, 1, wid, lane);
  barf();
  __builtin_amdgcn_s_setprio(1);
#pragma unroll
  for (int m = 0; m < 4; ++m)
#pragma unroll
    for (int n = 0; n < 2; ++n)
#pragma unroll
      for (int ks = 0; ks < 2; ++ks)
        acc[m + 4][n + 2] = __builtin_amdgcn_mfma_f32_16x16x32_bf16(a[m][ks], b1[n][ks], acc[m + 4][n + 2], 0, 0, 0);
  __builtin_amdgcn_s_setprio(0);
  barf();

  // ---- phase 4: MFMA A23 x B01 (regs only); stage (t+2).A-half0 into read-parity buf
  if (smode == 2) stage_unit(Ab, aL, t + 2, 0, wid, lane);  // safe: all t-reads retired by ph3
  barf();
  __builtin_amdgcn_s_setprio(1);
#pragma unroll
  for (int m = 0; m < 4; ++m)
#pragma unroll
    for (int n = 0; n < 2; ++n)
#pragma unroll
      for (int ks = 0; ks < 2; ++ks)
        acc[m + 4][n] = __builtin_amdgcn_mfma_f32_16x16x32_bf16(a[m][ks], b0[n][ks], acc[m + 4][n], 0, 0, 0);
  __builtin_amdgcn_s_setprio(0);
  if (smode == 2) vmcnt2();        // ledger: only (t+2).A0 (2 loads) may stay in flight
  else if (smode == 1) vmcnt0();   // tail: tile7 fully staged, nothing younger
  barf();
}

__global__ __launch_bounds__(512, 2) void gemm8(const unsigned short* __restrict__ A,
                                                const unsigned short* __restrict__ B,
                                                const float* __restrict__ bias,
                                                float* __restrict__ C,
                                                float* __restrict__ pmaxT,
                                                float* __restrict__ psumT) {
  __shared__ char lds[131072];  // A dbuf 64K | B dbuf 64K
  const int tid  = threadIdx.x;
  const int lane = tid & 63;
  const int wid  = tid >> 6;           // 8 waves: 2M x 4N
  const int wr   = wid >> 2, wc = wid & 3;

  // bijective XCD chunking over the 32x32 block grid (8x16 blocks per XCD)
  const int bid = blockIdx.x;
  const int xcd = bid & 7;
  const int s   = bid >> 3;
  const int by  = (xcd >> 1) * 8 + (s >> 4);
  const int bx  = (xcd & 1) * 16 + (s & 15);
  const int row0 = by * 256, col0 = bx * 256;

  const char* Ab = (const char*)A + (size_t)row0 * 1024;
  const char* Bb = (const char*)B + (size_t)col0 * 1024;

  f32x4 acc[8][4] = {};

  // prologue: stage tile0 fully + tile1.A-half0; wait tile0 (2 younger in flight)
  stage_unit(Ab, lds, 0, 0, wid, lane);
  stage_unit(Ab, lds, 0, 1, wid, lane);
  stage_unit(Bb, lds + 65536, 0, 0, wid, lane);
  stage_unit(Bb, lds + 65536, 0, 1, wid, lane);
  stage_unit(Ab, lds + 32768, 1, 0, wid, lane);
  vmcnt2();
  barf();

  for (int t = 0; t < 6; ++t)
    kgroup(t, 2, lds, Ab, Bb, wr, wc, lane, wid, acc);
  kgroup(6, 1, lds, Ab, Bb, wr, wc, lane, wid, acc);
  kgroup(7, 0, lds, Ab, Bb, wr, wc, lane, wid, acc);

  // ---- epilogue: C-write + per-row {max, sumexp} over this block's 256 cols ----
  float* pmS = (float*)lds;           // [4][256]
  float* psS = (float*)lds + 1024;    // [4][256]
  const int cg = lane & 15, g = lane >> 4;

  float bv[4];
#pragma unroll
  for (int n = 0; n < 4; ++n) bv[n] = bias[col0 + wc * 64 + n * 16 + cg];

#pragma unroll
  for (int m = 0; m < 8; ++m) {
#pragma unroll
    for (int rr = 0; rr < 4; ++rr) {
      const int R = wr * 128 + m * 16 + 4 * g + rr;
      const size_t rowg = row0 + R;
      float vmx = -1e30f, vsm = 0.f;
#pragma unroll
      for (int n = 0; n < 4; ++n) {
        const float v = acc[m][n][rr] + bv[n];
        C[rowg * V_ + col0 + wc * 64 + n * 16 + cg] = v;
        vmx = fmaxf(vmx, v);
        vsm += __expf(v);
      }
#pragma unroll
      for (int o = 1; o < 16; o <<= 1) {
        vmx = fmaxf(vmx, __shfl_xor(vmx, o));
        vsm += __shfl_xor(vsm, o);
      }
      if (cg == 0) { pmS[wc * 256 + R] = vmx; psS[wc * 256 + R] = vsm; }
    }
  }
  __syncthreads();
  if (tid < 256) {
    float mx = fmaxf(fmaxf(pmS[tid], pmS[256 + tid]), fmaxf(pmS[512 + tid], pmS[768 + tid]));
    float sm = psS[tid] + psS[256 + tid] + psS[512 + tid] + psS[768 + tid];
    pmaxT[(size_t)bx * BT_ + row0 + tid] = mx;
    psumT[(size_t)bx * BT_ + row0 + tid] = sm;
  }
}

// ---- pass 2: per-row reduce partials, exact-fp32 argmax rescue, softmax sweep ----
__global__ __launch_bounds__(256) void row_finish(const float* __restrict__ logits,
                                                  const float* __restrict__ pmaxT,
                                                  const float* __restrict__ psumT,
                                                  const float* __restrict__ xf,
                                                  const float* __restrict__ wf,
                                                  const float* __restrict__ bias,
                                                  float* __restrict__ tokf,
                                                  float* __restrict__ soft) {
  const int row  = blockIdx.x;
  const int tid  = threadIdx.x;
  const int lane = tid & 63;
  const int wv   = tid >> 6;

  const int tl = lane & 31;                          // tile index (dup in high lanes)
  const float pm = pmaxT[(size_t)tl * BT_ + row];
  const float ps = psumT[(size_t)tl * BT_ + row];
  float m = pm, s = ps;
#pragma unroll
  for (int o = 1; o < 32; o <<= 1) {
    m = fmaxf(m, __shfl_xor(m, o));
    s += __shfl_xor(s, o);
  }
  const float si = 1.0f / s;

  const float* L = logits + (size_t)row * V_;
  float*       S = soft   + (size_t)row * V_;
  const float4* L4 = (const float4*)(L + 3);  // region base ==1 mod 4 -> +3 is 16B-aligned
  float4*       S4 = (float4*)(S + 3);

  if (wv == 0) {
    // ---- argmax rescue on wave 0 ----
    const float thr = m - TAU;
    unsigned long long tmask = __ballot(pm >= thr) & 0xFFFFFFFFull;
    float bestv = -1e30f;
    int   besti = 0x7fffffff;
    const float4* xr4 = (const float4*)(xf + (size_t)row * D_);
    while (tmask) {
      const int t = __ffsll(tmask) - 1;
      tmask &= tmask - 1;
      const float* Lr = L + t * 256;
#pragma unroll
      for (int kq = 0; kq < 4; ++kq) {
        const float lv = Lr[kq * 64 + lane];
        unsigned long long c = __ballot(lv >= thr);
        while (c) {
          const int j = __ffsll(c) - 1;
          c &= c - 1;
          const int col = t * 256 + kq * 64 + j;
          const float4* wr4 = (const float4*)(wf + (size_t)col * D_);
          float p = 0.f;
#pragma unroll
          for (int q = 0; q < 2; ++q) {
            const float4 av = xr4[lane + 64 * q];
            const float4 bvv = wr4[lane + 64 * q];
            p += av.x * bvv.x + av.y * bvv.y + av.z * bvv.z + av.w * bvv.w;
          }
#pragma unroll
          for (int o = 1; o < 64; o <<= 1) p += __shfl_xor(p, o);
          const float tot = p + bias[col];
          if (tot > bestv || (tot == bestv && col < besti)) { bestv = tot; besti = col; }
        }
      }
    }
    if (lane == 0) tokf[row] = (float)besti;
    // wave0's small static sweep share + head/tail
    if (lane < 3)  S[lane] = __expf(L[lane]) * si;
    if (lane == 3) S[8191] = __expf(L[8191]) * si;
#pragma unroll
    for (int k = 0; k < 2; ++k) {
      const int i = 1920 + k * 64 + lane;
      if (i < 2047) {
        const float4 v = L4[i];
        float4 o;
        o.x = __expf(v.x) * si; o.y = __expf(v.y) * si;
        o.z = __expf(v.z) * si; o.w = __expf(v.w) * si;
        S4[i] = o;
      }
    }
  } else {
    // waves 1-3: bulk sweep [0, 1920) immediately, no barrier
    const int t = tid - 64;  // 0..191
#pragma unroll
    for (int k = 0; k < 10; ++k) {
      const int i = k * 192 + t;
      const float4 v = L4[i];
      float4 o;
      o.x = __expf(v.x) * si; o.y = __expf(v.y) * si;
      o.z = __expf(v.z) * si; o.w = __expf(v.w) * si;
      S4[i] = o;
    }
  }
}

// ---------------- pass 3: quantized gather + commitment loss ----------------
__global__ __launch_bounds__(256) void finalize_k(const float* __restrict__ tokf,
                                                  const float* __restrict__ cb,
                                                  const float* __restrict__ xf,
                                                  float* __restrict__ q,
                                                  float* __restrict__ loss) {
  const int row  = blockIdx.x * 4 + (threadIdx.x >> 6);
  const int lane = threadIdx.x & 63;
  const int idx  = (int)tokf[row];
  const float4* cr = (const float4*)(cb + (size_t)idx * D_);
  const float4* xr = (const float4*)(xf + (size_t)row * D_);
  float4* qr = (float4*)(q + (size_t)row * D_);
  float ls = 0.f;
#pragma unroll
  for (int j = 0; j < 2; ++j) {
    const int c = lane + j * 64;
    const float4 cv = cr[c];
    const float4 xv = xr[c];
    qr[c] = cv;
    const float dx = cv.x - xv.x, dy = cv.y - xv.y, dz = cv.z - xv.z, dw = cv.w - xv.w;
    ls += dx * dx + dy * dy + dz * dz + dw * dw;
  }
#pragma unroll
  for (int o = 32; o; o >>= 1) ls += __shfl_xor(ls, o);
  if (lane == 0) atomicAdd(loss, ls * (1.0f / 4194304.0f));
}

extern "C" void kernel_launch(void* const* d_in, const int* in_sizes, int n_in,
                              void* d_out, int out_size, void* d_ws, size_t ws_size,
                              hipStream_t stream) {
  const float* x  = (const float*)d_in[0];  // inputs   [8192][512]
  const float* cb = (const float*)d_in[1];  // codebook [8192][512]
  const float* wl = (const float*)d_in[2];  // W_logits [8192][512]
  const float* bl = (const float*)d_in[3];  // b_logits [8192]
  float* out = (float*)d_out;

  float* qout   = out + OFF_Q;
  float* tokf   = out + OFF_TOK;
  float* loss   = out + OFF_LOSS;
  float* soft   = out + OFF_SOFT;
  float* logits = out + OFF_LOGITS;

  // scratch carved from output regions (each rewritten later in the pipeline):
  unsigned short* Abf = (unsigned short*)(out + STAGE_F);  // in soft region
  unsigned short* Wbf = Abf + (size_t)BT_ * D_;
  float* pmaxT = qout;            // [32][8192] in quantized region (finalize overwrites last)
  float* psumT = qout + 262144;   // [32][8192]

  hipMemsetAsync(loss, 0, 4, stream);

  to_bf16_k<<<2048, 256, 0, stream>>>((const float4*)x, (const float4*)wl,
                                      (u16x4*)Abf, (u16x4*)Wbf);
  gemm8<<<1024, 512, 0, stream>>>(Abf, Wbf, bl, logits, pmaxT, psumT);
  row_finish<<<8192, 256, 0, stream>>>(logits, pmaxT, psumT, x, wl, bl, tokf, soft);
  finalize_k<<<2048, 256, 0, stream>>>(tokf, cb, x, qout, loss);
}